// Round 9
// baseline (347.531 us; speedup 1.0000x reference)
//
#include <hip/hip_runtime.h>
#include <math.h>

// ProtoLoss: loss = mean_n( -2*sim[n,fam[n]] + logsumexp_f(4*sim[n,f]) )
// sim = (e.p)/(||e||*||p||) -- scale-invariant in p: p_hat = raw_sum/||raw_sum||.
// N=262144, D=128, F=64.
//
// Session ledger:
//  - LDS fp32 atomics: ~0.3 lane-ops/cyc/CU -> per-element-atomic segment sum
//    floors at ~150us (r1/r3).
//  - Two 512MB harness poison-fills (~77.5us each) sit INSIDE the timed
//    window: ~155us of dur_us is untouchable (r0/r5/r6/r8 top-5).
//  - Segment-sum-as-MFMA with one-hot A (bf16-exact) + hi/lo bf16 split of
//    emb (hi=trunc, lo=RNE(x-hi)) is fp32-exact to ~2^-17: absmax 0.0 (r4+).
//  - Keep MFMA accumulator <= 32 VGPRs (r4: acc[4][8] spilled, 301MB scratch).
//  - No __launch_bounds__ min-wave floor beyond the live set (r6 spill).
//  - NO hipLaunchCooperativeKernel (r7: container death). Device-scope
//    atomics + __threadfence + all-resident spin (this round) is the
//    sanctioned grid-sync (G16); 512 blocks @ 2/CU are all co-resident.
//  - Bench noise ~±8-10us (r5 235.1 / r8 246.5 with neutral change).
//
// Structure:
// AB) 512 blocks x 256 thr (2 blk/CU, all resident). Phase A = r5 pass_a:
//     wave w owns dim-slice [32w,+32) of the block's 512 rows; acc[4][2]=32
//     VGPRs; one-hot MFMA segment sum; direct reg->psum. Then release fence
//     + device atomicAdd(cnt); blocks 0..63 spin (acquire) until cnt==512
//     and run phase B (reduce 512 partials + normalize -> protoB bf16).
// C)  2048 blocks x 256 thr: swapped-operand MFMA sims + fused lse epilogue;
//     one unsafeAtomicAdd per block (r1<->r2: neutral).
// cnt is zeroed by a 4-byte hipMemsetAsync (graph-safe, r0 precedent);
// out[0] zeroed by block 0 of pass_ab (stream-ordered before pass_c).

#define D_DIM 128
#define F_NUM 64
#define ROWS_A 512

typedef __attribute__((ext_vector_type(8))) short short8;
typedef __attribute__((ext_vector_type(4))) float f32x4;

static __device__ __forceinline__ unsigned short f2bf(float x) {
  union { float f; unsigned u; } v; v.f = x;
  unsigned r = v.u + 0x7FFFu + ((v.u >> 16) & 1u);   // RNE
  return (unsigned short)(r >> 16);
}

// ---------------- Pass AB ----------------------------------------------------
__global__ __launch_bounds__(256, 2) void pass_ab(
    const float* __restrict__ emb, const int* __restrict__ fam,
    float* __restrict__ psum, unsigned short* __restrict__ protoB,
    float* __restrict__ out, unsigned int* __restrict__ cnt, int nBlk)
{
  __shared__ float4 sh[256];                 // phase B reduce buffer (4 KB)
  int t = threadIdx.x, blk = blockIdx.x;
  int w = t >> 6, lane = t & 63;
  int m16 = lane & 15, q = lane >> 4;

  if (blk == 0 && t == 0) out[0] = 0.f;      // stream-ordered before pass_c

  // ---------------- Phase A: segment sum as MFMA (r5-proven) -------------
  {
    int dimBase = w * 32;                    // wave's private dim slice
    f32x4 acc[4][2] = {};                    // 32 VGPRs, register-resident
    int rb0 = blk * ROWS_A;

    #pragma unroll 2
    for (int s = 0; s < ROWS_A / 32; ++s) {
      int rb = rb0 + s * 32;                 // K-slab of 32 rows
      const int* fp = fam + rb + q * 8;      // k = q*8 + j (verified conv.)
      int fj[8];
      #pragma unroll
      for (int j = 0; j < 8; ++j) fj[j] = fp[j];

      // B-operand: lane m16 = dim; 16 lanes x 4B = contiguous 64B segments
      const float* eb = emb + (size_t)(rb + q * 8) * D_DIM + dimBase + m16;
      float x0[8], x1[8];
      #pragma unroll
      for (int j = 0; j < 8; ++j) {
        x0[j] = eb[j * D_DIM];               // nt=0: dims dimBase+m16
        x1[j] = eb[j * D_DIM + 16];          // nt=1: dims dimBase+16+m16
      }

      // one-hot A-frags: A[m16][k] = (fam[k]==ft*16+m16) ? 1.0bf16 : 0
      short8 af[4];
      #pragma unroll
      for (int ft = 0; ft < 4; ++ft)
        #pragma unroll
        for (int j = 0; j < 8; ++j)
          af[ft][j] = (fj[j] == ft * 16 + m16) ? (short)0x3F80 : (short)0;

      short8 h0, l0, h1, l1;                 // hi = truncate, lo = RNE(x-hi)
      #pragma unroll
      for (int j = 0; j < 8; ++j) {
        unsigned b0 = __float_as_uint(x0[j]);
        h0[j] = (short)(b0 >> 16);
        l0[j] = (short)f2bf(x0[j] - __uint_as_float(b0 & 0xFFFF0000u));
        unsigned b1 = __float_as_uint(x1[j]);
        h1[j] = (short)(b1 >> 16);
        l1[j] = (short)f2bf(x1[j] - __uint_as_float(b1 & 0xFFFF0000u));
      }

      #pragma unroll
      for (int ft = 0; ft < 4; ++ft) {
        acc[ft][0] = __builtin_amdgcn_mfma_f32_16x16x32_bf16(af[ft], h0, acc[ft][0], 0, 0, 0);
        acc[ft][0] = __builtin_amdgcn_mfma_f32_16x16x32_bf16(af[ft], l0, acc[ft][0], 0, 0, 0);
        acc[ft][1] = __builtin_amdgcn_mfma_f32_16x16x32_bf16(af[ft], h1, acc[ft][1], 0, 0, 0);
        acc[ft][1] = __builtin_amdgcn_mfma_f32_16x16x32_bf16(af[ft], l1, acc[ft][1], 0, 0, 0);
      }
    }

    // D[fam = ft*16+q*4+i][dim = dimBase+nt*16+m16]; 16-lane 64B lines
    float* outp = psum + (size_t)blk * (F_NUM * D_DIM) + dimBase + m16;
    #pragma unroll
    for (int ft = 0; ft < 4; ++ft)
      #pragma unroll
      for (int i = 0; i < 4; ++i) {
        int f = ft * 16 + q * 4 + i;
        outp[(size_t)f * D_DIM]      = acc[ft][0][i];
        outp[(size_t)f * D_DIM + 16] = acc[ft][1][i];
      }
  }

  // ---------------- grid arrival: release psum, count in -----------------
  __threadfence();                           // device-scope release of psum
  __syncthreads();                           // whole block's stores fenced
  if (t == 0)
    __hip_atomic_fetch_add(cnt, 1u, __ATOMIC_ACQ_REL, __HIP_MEMORY_SCOPE_AGENT);
  if (blk >= F_NUM) return;                  // only blocks 0..63 run phase B

  // all 512 blocks are co-resident (2 blk/CU) -> spin cannot deadlock
  if (t == 0) {
    while (__hip_atomic_load(cnt, __ATOMIC_ACQUIRE, __HIP_MEMORY_SCOPE_AGENT)
           < (unsigned)nBlk)
      __builtin_amdgcn_s_sleep(8);
  }
  __syncthreads();
  __threadfence();                           // acquire: see all psum stores

  // ---------------- Phase B: reduce partials + normalize ------------------
  {
    int f = blk, d4 = t & 31, pg = t >> 5;   // 8 partial-groups
    const float4* p4 = (const float4*)psum;  // partial stride 2048 float4
    float4 s = make_float4(0.f, 0.f, 0.f, 0.f);
    int per = nBlk >> 3;                     // 64
    #pragma unroll 8
    for (int i = 0; i < per; ++i) {
      float4 a = p4[(size_t)(pg + 8 * i) * (F_NUM * D_DIM / 4) + f * 32 + d4];
      s.x += a.x; s.y += a.y; s.z += a.z; s.w += a.w;
    }
    sh[t] = s;
    __syncthreads();
    if (t < 32) {
      float4 rsum = sh[t];
      #pragma unroll
      for (int g = 1; g < 8; ++g) {
        float4 a = sh[g * 32 + t];
        rsum.x += a.x; rsum.y += a.y; rsum.z += a.z; rsum.w += a.w;
      }
      float n2 = rsum.x * rsum.x + rsum.y * rsum.y +
                 rsum.z * rsum.z + rsum.w * rsum.w;
      n2 += __shfl_xor(n2, 1);  n2 += __shfl_xor(n2, 2);  n2 += __shfl_xor(n2, 4);
      n2 += __shfl_xor(n2, 8);  n2 += __shfl_xor(n2, 16);
      float inv = rsqrtf(fmaxf(n2, 1e-24f)); // empty family -> p_hat=0 -> sim=0
      ushort4 u;
      u.x = f2bf(rsum.x * inv); u.y = f2bf(rsum.y * inv);
      u.z = f2bf(rsum.z * inv); u.w = f2bf(rsum.w * inv);
      ((ushort4*)protoB)[f * 32 + t] = u;    // natural [f][128] bf16
    }
  }
}

// ---------------- Pass C -----------------------------------------------------
// N/128 blocks x 256 thr. Wave handles 32 samples (2 st-tiles of 16).
// mfma(A=proto_frag, B=sample_frag): D[f-local q*4+reg][sample m16].
__global__ __launch_bounds__(256) void pass_c(
    const float* __restrict__ emb, const int* __restrict__ fam,
    const unsigned short* __restrict__ protoB,
    float* __restrict__ out, float invN)
{
  __shared__ float sWp[4];
  int t = threadIdx.x, w = t >> 6, lane = t & 63;
  int m16 = lane & 15, q = lane >> 4;
  int S0 = blockIdx.x * 128 + w * 32;

  const float4* E4 = (const float4*)emb;     // row stride 32 float4
  const short8* P8 = (const short8*)protoB;  // row stride 16 chunks

  size_t e0 = (size_t)(S0 + m16) * 32 + q * 2;       // st=0
  size_t e1 = e0 + 16 * 32;                          // st=1
  int pb = m16 * 16 + q;                             // proto frag base (ft=0)

  f32x4 acc[2][4] = {};
  float s2a = 0.f, s2b = 0.f;

  #pragma unroll
  for (int ks = 0; ks < 4; ++ks) {
    short8 a0 = P8[pb + ks * 4];             // protos ft=0 (rows 0..15)
    short8 a1 = P8[pb + 256 + ks * 4];       // ft=1
    short8 a2 = P8[pb + 512 + ks * 4];       // ft=2
    short8 a3 = P8[pb + 768 + ks * 4];       // ft=3

    float4 va = E4[e0 + ks * 8], vb = E4[e0 + ks * 8 + 1];
    s2a += va.x * va.x + va.y * va.y + va.z * va.z + va.w * va.w +
           vb.x * vb.x + vb.y * vb.y + vb.z * vb.z + vb.w * vb.w;
    short8 b0;
    b0[0] = (short)f2bf(va.x); b0[1] = (short)f2bf(va.y);
    b0[2] = (short)f2bf(va.z); b0[3] = (short)f2bf(va.w);
    b0[4] = (short)f2bf(vb.x); b0[5] = (short)f2bf(vb.y);
    b0[6] = (short)f2bf(vb.z); b0[7] = (short)f2bf(vb.w);
    acc[0][0] = __builtin_amdgcn_mfma_f32_16x16x32_bf16(a0, b0, acc[0][0], 0, 0, 0);
    acc[0][1] = __builtin_amdgcn_mfma_f32_16x16x32_bf16(a1, b0, acc[0][1], 0, 0, 0);
    acc[0][2] = __builtin_amdgcn_mfma_f32_16x16x32_bf16(a2, b0, acc[0][2], 0, 0, 0);
    acc[0][3] = __builtin_amdgcn_mfma_f32_16x16x32_bf16(a3, b0, acc[0][3], 0, 0, 0);

    float4 vc = E4[e1 + ks * 8], vd = E4[e1 + ks * 8 + 1];
    s2b += vc.x * vc.x + vc.y * vc.y + vc.z * vc.z + vc.w * vc.w +
           vd.x * vd.x + vd.y * vd.y + vd.z * vd.z + vd.w * vd.w;
    short8 b1;
    b1[0] = (short)f2bf(vc.x); b1[1] = (short)f2bf(vc.y);
    b1[2] = (short)f2bf(vc.z); b1[3] = (short)f2bf(vc.w);
    b1[4] = (short)f2bf(vd.x); b1[5] = (short)f2bf(vd.y);
    b1[6] = (short)f2bf(vd.z); b1[7] = (short)f2bf(vd.w);
    acc[1][0] = __builtin_amdgcn_mfma_f32_16x16x32_bf16(a0, b1, acc[1][0], 0, 0, 0);
    acc[1][1] = __builtin_amdgcn_mfma_f32_16x16x32_bf16(a1, b1, acc[1][1], 0, 0, 0);
    acc[1][2] = __builtin_amdgcn_mfma_f32_16x16x32_bf16(a2, b1, acc[1][2], 0, 0, 0);
    acc[1][3] = __builtin_amdgcn_mfma_f32_16x16x32_bf16(a3, b1, acc[1][3], 0, 0, 0);
  }

  // per-sample norms: lane covers dims {ks*32+q*8..+8}; q-reduce completes 128
  s2a += __shfl_xor(s2a, 16); s2a += __shfl_xor(s2a, 32);
  s2b += __shfl_xor(s2b, 16); s2b += __shfl_xor(s2b, 32);
  float rn0 = rsqrtf(fmaxf(s2a, 1e-20f));
  float rn1 = rsqrtf(fmaxf(s2b, 1e-20f));
  int fr0 = fam[S0 + m16], fr1 = fam[S0 + 16 + m16];

  float wp = 0.f;
  {
    int fh = fr0 >> 4, fq = (fr0 >> 2) & 3, fl = fr0 & 3;
    float es = 0.f, ps = 0.f;
    #pragma unroll
    for (int ft = 0; ft < 4; ++ft)
      #pragma unroll
      for (int i = 0; i < 4; ++i) {
        float sim = acc[0][ft][i] * rn0;     // f = ft*16 + q*4 + i
        es += __expf(4.f * sim - 4.f);       // arg in [-8, ~0]
        ps += (fq == q && fh == ft && fl == i) ? sim : 0.f;
      }
    es += __shfl_xor(es, 16); es += __shfl_xor(es, 32);
    ps += __shfl_xor(ps, 16); ps += __shfl_xor(ps, 32);
    if (q == 0) wp += 4.f + __logf(es) - 2.f * ps;
  }
  {
    int fh = fr1 >> 4, fq = (fr1 >> 2) & 3, fl = fr1 & 3;
    float es = 0.f, ps = 0.f;
    #pragma unroll
    for (int ft = 0; ft < 4; ++ft)
      #pragma unroll
      for (int i = 0; i < 4; ++i) {
        float sim = acc[1][ft][i] * rn1;
        es += __expf(4.f * sim - 4.f);
        ps += (fq == q && fh == ft && fl == i) ? sim : 0.f;
      }
    es += __shfl_xor(es, 16); es += __shfl_xor(es, 32);
    ps += __shfl_xor(ps, 16); ps += __shfl_xor(ps, 32);
    if (q == 0) wp += 4.f + __logf(es) - 2.f * ps;
  }

  // wave total (q!=0 lanes hold 0)
  wp += __shfl_xor(wp, 1);  wp += __shfl_xor(wp, 2);  wp += __shfl_xor(wp, 4);
  wp += __shfl_xor(wp, 8);  wp += __shfl_xor(wp, 16); wp += __shfl_xor(wp, 32);
  if (lane == 0) sWp[w] = wp;
  __syncthreads();
  if (t == 0)
    unsafeAtomicAdd(out, (sWp[0] + sWp[1] + sWp[2] + sWp[3]) * invN);
}

extern "C" void kernel_launch(void* const* d_in, const int* in_sizes, int n_in,
                              void* d_out, int out_size, void* d_ws, size_t ws_size,
                              hipStream_t stream) {
  const float* emb = (const float*)d_in[0];
  const int* fam = (const int*)d_in[1];
  int N = in_sizes[0] / D_DIM;               // 262144
  int blocksA = N / ROWS_A;                  // 512
  int blocksC = N / 128;                     // 2048

  // ws (float units): psum[512*8192] | protoB(8192 ushort = 4096 f) | cnt
  float* ws = (float*)d_ws;
  float* psum = ws;
  size_t off = (size_t)blocksA * (F_NUM * D_DIM);
  unsigned short* protoB = (unsigned short*)(ws + off); off += (F_NUM * D_DIM) / 2;
  unsigned int* cnt = (unsigned int*)(ws + off);

  (void)hipMemsetAsync(cnt, 0, sizeof(unsigned int), stream);
  pass_ab<<<blocksA, 256, 0, stream>>>(emb, fam, psum, protoB,
                                       (float*)d_out, cnt, blocksA);
  pass_c<<<blocksC, 256, 0, stream>>>(emb, fam, protoB, (float*)d_out,
                                      1.0f / (float)N);
}

// Round 10
// 235.369 us; speedup vs baseline: 1.4765x; 1.4765x over previous
//
#include <hip/hip_runtime.h>
#include <math.h>

// ProtoLoss: loss = mean_n( -2*sim[n,fam[n]] + logsumexp_f(4*sim[n,f]) )
// sim = (e.p)/(||e||*||p||) -- scale-invariant in p: p_hat = raw_sum/||raw_sum||.
// N=262144, D=128, F=64.
//
// EXACT r5 revert -- best measured 235.1us. Session ledger:
//  - LDS fp32 atomics: ~0.3 lane-ops/cyc/CU -> per-element-atomic segment sum
//    floors at ~150us (r1/r3).
//  - Two 512MB harness poison-fills (~77.5us each) sit INSIDE the timed
//    window: ~155us of dur_us is untouchable (r0/r5/r6/r8/r9 top-5).
//  - Segment-sum-as-MFMA with one-hot A (bf16-exact) + hi/lo bf16 split of
//    emb (hi=trunc, lo=RNE(x-hi)) is fp32-exact to ~2^-17: absmax 0.0 (r4+).
//  - Keep MFMA accumulator <= 32 VGPRs (r4: acc[4][8] spilled, 301MB scratch).
//  - No __launch_bounds__ min-wave floor beyond the live set (r6: (256,4)
//    capped VGPR 128 -> spill -> +16us).
//  - NO hipLaunchCooperativeKernel (r7: container death).
//  - NO phase-fusion into pass_a (r9: merging phase B + spin flipped the
//    allocator to VGPR=52 -> serialized gathers -> 166us, r1's fingerprint).
//    pass_a's fast codegen is fragile; keep it standalone.
//  - Bench noise ~±10us (r5 235.1 vs r8 246.5 on a neutral change).
//
// A) 512 blocks x 256 thr (2 blk/CU). Wave w owns dim-slice [32w,+32) for the
//    block's 512 rows -> acc[4][2] = 32 VGPRs, register-resident, no LDS,
//    no barrier. Per 32-row K-slab: 8 fam dwords, one-hot A-frags, emb
//    gathers (64B segments), hi/lo bf16 split, 16 MFMA. Direct reg->psum.
// B) 64 blocks x 256 thr: reduce 512 partials + normalize -> protoB bf16.
// C) 2048 blocks x 256 thr: swapped-operand MFMA sims + fused lse epilogue;
//    per-block partial -> part[bid].
// D) 1-block reduce of 2048 partials -> d_out.

#define D_DIM 128
#define F_NUM 64
#define ROWS_A 512

typedef __attribute__((ext_vector_type(8))) short short8;
typedef __attribute__((ext_vector_type(4))) float f32x4;

static __device__ __forceinline__ unsigned short f2bf(float x) {
  union { float f; unsigned u; } v; v.f = x;
  unsigned r = v.u + 0x7FFFu + ((v.u >> 16) & 1u);   // RNE
  return (unsigned short)(r >> 16);
}

// ---------------- Pass A -----------------------------------------------------
__global__ __launch_bounds__(256, 2) void pass_a(
    const float* __restrict__ emb, const int* __restrict__ fam,
    float* __restrict__ psum)
{
  int t = threadIdx.x, w = t >> 6, lane = t & 63;
  int m16 = lane & 15, q = lane >> 4;
  int dimBase = w * 32;                      // wave's private dim slice

  f32x4 acc[4][2] = {};                      // [f-tile][dim-tile] = 32 VGPRs
  int rb0 = blockIdx.x * ROWS_A;

  #pragma unroll 2
  for (int s = 0; s < ROWS_A / 32; ++s) {
    int rb = rb0 + s * 32;                   // K-slab of 32 rows
    // fam for this lane's k-slots: k = q*8 + j (verified A convention)
    const int* fp = fam + rb + q * 8;
    int fj[8];
    #pragma unroll
    for (int j = 0; j < 8; ++j) fj[j] = fp[j];

    // B-operand: lane m16 = dim, k = q*8+j. One addr VGPR + imm offsets;
    // 16 lanes x 4B = contiguous 64B segments.
    const float* eb = emb + (size_t)(rb + q * 8) * D_DIM + dimBase + m16;
    float x0[8], x1[8];
    #pragma unroll
    for (int j = 0; j < 8; ++j) {
      x0[j] = eb[j * D_DIM];                 // nt=0: dims dimBase+m16
      x1[j] = eb[j * D_DIM + 16];            // nt=1: dims dimBase+16+m16
    }

    // one-hot A-frags: A[m16][k] = (fam[k] == ft*16+m16) ? 1.0bf16 : 0
    short8 af[4];
    #pragma unroll
    for (int ft = 0; ft < 4; ++ft)
      #pragma unroll
      for (int j = 0; j < 8; ++j)
        af[ft][j] = (fj[j] == ft * 16 + m16) ? (short)0x3F80 : (short)0;

    short8 h0, l0, h1, l1;                   // hi = truncate, lo = RNE(x-hi)
    #pragma unroll
    for (int j = 0; j < 8; ++j) {
      unsigned b0 = __float_as_uint(x0[j]);
      h0[j] = (short)(b0 >> 16);
      l0[j] = (short)f2bf(x0[j] - __uint_as_float(b0 & 0xFFFF0000u));
      unsigned b1 = __float_as_uint(x1[j]);
      h1[j] = (short)(b1 >> 16);
      l1[j] = (short)f2bf(x1[j] - __uint_as_float(b1 & 0xFFFF0000u));
    }

    #pragma unroll
    for (int ft = 0; ft < 4; ++ft) {
      acc[ft][0] = __builtin_amdgcn_mfma_f32_16x16x32_bf16(af[ft], h0, acc[ft][0], 0, 0, 0);
      acc[ft][0] = __builtin_amdgcn_mfma_f32_16x16x32_bf16(af[ft], l0, acc[ft][0], 0, 0, 0);
      acc[ft][1] = __builtin_amdgcn_mfma_f32_16x16x32_bf16(af[ft], h1, acc[ft][1], 0, 0, 0);
      acc[ft][1] = __builtin_amdgcn_mfma_f32_16x16x32_bf16(af[ft], l1, acc[ft][1], 0, 0, 0);
    }
  }

  // D[fam = ft*16+q*4+i][dim = dimBase+nt*16+m16]; 16-lane groups = 64B lines
  float* outp = psum + (size_t)blockIdx.x * (F_NUM * D_DIM) + dimBase + m16;
  #pragma unroll
  for (int ft = 0; ft < 4; ++ft)
    #pragma unroll
    for (int i = 0; i < 4; ++i) {
      int f = ft * 16 + q * 4 + i;
      outp[(size_t)f * D_DIM]      = acc[ft][0][i];
      outp[(size_t)f * D_DIM + 16] = acc[ft][1][i];
    }
}

// ---------------- Pass B (fused reduce + normalize) --------------------------
// 64 blocks x 256 thr. Block f: thread (d4=t&31, pg=t>>5) sums 64 partials of
// float4 d4; LDS combine 8 groups; lanes 0..31 normalize + write bf16 row.
__global__ __launch_bounds__(256) void pass_b(
    const float* __restrict__ psum, unsigned short* __restrict__ protoB,
    int nPart)
{
  __shared__ float4 sh[256];
  int t = threadIdx.x, f = blockIdx.x;
  int d4 = t & 31, pg = t >> 5;
  const float4* p4 = (const float4*)psum;    // partial stride 2048 float4
  float4 s = make_float4(0.f, 0.f, 0.f, 0.f);
  int per = nPart >> 3;                      // 64
  #pragma unroll 8
  for (int i = 0; i < per; ++i) {
    float4 a = p4[(size_t)(pg + 8 * i) * (F_NUM * D_DIM / 4) + f * 32 + d4];
    s.x += a.x; s.y += a.y; s.z += a.z; s.w += a.w;
  }
  sh[t] = s;
  __syncthreads();
  if (t < 32) {
    float4 rsum = sh[t];
    #pragma unroll
    for (int g = 1; g < 8; ++g) {
      float4 a = sh[g * 32 + t];
      rsum.x += a.x; rsum.y += a.y; rsum.z += a.z; rsum.w += a.w;
    }
    float n2 = rsum.x * rsum.x + rsum.y * rsum.y +
               rsum.z * rsum.z + rsum.w * rsum.w;
    n2 += __shfl_xor(n2, 1);  n2 += __shfl_xor(n2, 2);  n2 += __shfl_xor(n2, 4);
    n2 += __shfl_xor(n2, 8);  n2 += __shfl_xor(n2, 16);
    float inv = rsqrtf(fmaxf(n2, 1e-24f));   // empty family -> p_hat=0 -> sim=0
    ushort4 u;
    u.x = f2bf(rsum.x * inv); u.y = f2bf(rsum.y * inv);
    u.z = f2bf(rsum.z * inv); u.w = f2bf(rsum.w * inv);
    ((ushort4*)protoB)[f * 32 + t] = u;      // natural [f][128] bf16
  }
}

// ---------------- Pass C -----------------------------------------------------
// N/128 blocks x 256 thr. Wave handles 32 samples (2 st-tiles of 16).
// mfma(A=proto_frag, B=sample_frag): D[f-local q*4+reg][sample m16].
__global__ __launch_bounds__(256) void pass_c(
    const float* __restrict__ emb, const int* __restrict__ fam,
    const unsigned short* __restrict__ protoB, float* __restrict__ part)
{
  __shared__ float sWp[4];
  int t = threadIdx.x, w = t >> 6, lane = t & 63;
  int m16 = lane & 15, q = lane >> 4;
  int S0 = blockIdx.x * 128 + w * 32;

  const float4* E4 = (const float4*)emb;     // row stride 32 float4
  const short8* P8 = (const short8*)protoB;  // row stride 16 chunks

  size_t e0 = (size_t)(S0 + m16) * 32 + q * 2;       // st=0
  size_t e1 = e0 + 16 * 32;                          // st=1
  int pb = m16 * 16 + q;                             // proto frag base (ft=0)

  f32x4 acc[2][4] = {};
  float s2a = 0.f, s2b = 0.f;

  #pragma unroll
  for (int ks = 0; ks < 4; ++ks) {
    short8 a0 = P8[pb + ks * 4];             // protos ft=0 (rows 0..15)
    short8 a1 = P8[pb + 256 + ks * 4];       // ft=1
    short8 a2 = P8[pb + 512 + ks * 4];       // ft=2
    short8 a3 = P8[pb + 768 + ks * 4];       // ft=3

    float4 va = E4[e0 + ks * 8], vb = E4[e0 + ks * 8 + 1];
    s2a += va.x * va.x + va.y * va.y + va.z * va.z + va.w * va.w +
           vb.x * vb.x + vb.y * vb.y + vb.z * vb.z + vb.w * vb.w;
    short8 b0;
    b0[0] = (short)f2bf(va.x); b0[1] = (short)f2bf(va.y);
    b0[2] = (short)f2bf(va.z); b0[3] = (short)f2bf(va.w);
    b0[4] = (short)f2bf(vb.x); b0[5] = (short)f2bf(vb.y);
    b0[6] = (short)f2bf(vb.z); b0[7] = (short)f2bf(vb.w);
    acc[0][0] = __builtin_amdgcn_mfma_f32_16x16x32_bf16(a0, b0, acc[0][0], 0, 0, 0);
    acc[0][1] = __builtin_amdgcn_mfma_f32_16x16x32_bf16(a1, b0, acc[0][1], 0, 0, 0);
    acc[0][2] = __builtin_amdgcn_mfma_f32_16x16x32_bf16(a2, b0, acc[0][2], 0, 0, 0);
    acc[0][3] = __builtin_amdgcn_mfma_f32_16x16x32_bf16(a3, b0, acc[0][3], 0, 0, 0);

    float4 vc = E4[e1 + ks * 8], vd = E4[e1 + ks * 8 + 1];
    s2b += vc.x * vc.x + vc.y * vc.y + vc.z * vc.z + vc.w * vc.w +
           vd.x * vd.x + vd.y * vd.y + vd.z * vd.z + vd.w * vd.w;
    short8 b1;
    b1[0] = (short)f2bf(vc.x); b1[1] = (short)f2bf(vc.y);
    b1[2] = (short)f2bf(vc.z); b1[3] = (short)f2bf(vc.w);
    b1[4] = (short)f2bf(vd.x); b1[5] = (short)f2bf(vd.y);
    b1[6] = (short)f2bf(vd.z); b1[7] = (short)f2bf(vd.w);
    acc[1][0] = __builtin_amdgcn_mfma_f32_16x16x32_bf16(a0, b1, acc[1][0], 0, 0, 0);
    acc[1][1] = __builtin_amdgcn_mfma_f32_16x16x32_bf16(a1, b1, acc[1][1], 0, 0, 0);
    acc[1][2] = __builtin_amdgcn_mfma_f32_16x16x32_bf16(a2, b1, acc[1][2], 0, 0, 0);
    acc[1][3] = __builtin_amdgcn_mfma_f32_16x16x32_bf16(a3, b1, acc[1][3], 0, 0, 0);
  }

  // per-sample norms: lane covers dims {ks*32+q*8..+8}; q-reduce completes 128
  s2a += __shfl_xor(s2a, 16); s2a += __shfl_xor(s2a, 32);
  s2b += __shfl_xor(s2b, 16); s2b += __shfl_xor(s2b, 32);
  float rn0 = rsqrtf(fmaxf(s2a, 1e-20f));
  float rn1 = rsqrtf(fmaxf(s2b, 1e-20f));
  int fr0 = fam[S0 + m16], fr1 = fam[S0 + 16 + m16];

  float wp = 0.f;
  {
    int fh = fr0 >> 4, fq = (fr0 >> 2) & 3, fl = fr0 & 3;
    float es = 0.f, ps = 0.f;
    #pragma unroll
    for (int ft = 0; ft < 4; ++ft)
      #pragma unroll
      for (int i = 0; i < 4; ++i) {
        float sim = acc[0][ft][i] * rn0;     // f = ft*16 + q*4 + i
        es += __expf(4.f * sim - 4.f);       // arg in [-8, ~0]
        ps += (fq == q && fh == ft && fl == i) ? sim : 0.f;
      }
    es += __shfl_xor(es, 16); es += __shfl_xor(es, 32);
    ps += __shfl_xor(ps, 16); ps += __shfl_xor(ps, 32);
    if (q == 0) wp += 4.f + __logf(es) - 2.f * ps;
  }
  {
    int fh = fr1 >> 4, fq = (fr1 >> 2) & 3, fl = fr1 & 3;
    float es = 0.f, ps = 0.f;
    #pragma unroll
    for (int ft = 0; ft < 4; ++ft)
      #pragma unroll
      for (int i = 0; i < 4; ++i) {
        float sim = acc[1][ft][i] * rn1;
        es += __expf(4.f * sim - 4.f);
        ps += (fq == q && fh == ft && fl == i) ? sim : 0.f;
      }
    es += __shfl_xor(es, 16); es += __shfl_xor(es, 32);
    ps += __shfl_xor(ps, 16); ps += __shfl_xor(ps, 32);
    if (q == 0) wp += 4.f + __logf(es) - 2.f * ps;
  }

  // wave total (q!=0 lanes hold 0)
  wp += __shfl_xor(wp, 1);  wp += __shfl_xor(wp, 2);  wp += __shfl_xor(wp, 4);
  wp += __shfl_xor(wp, 8);  wp += __shfl_xor(wp, 16); wp += __shfl_xor(wp, 32);
  if (lane == 0) sWp[w] = wp;
  __syncthreads();
  if (t == 0) part[blockIdx.x] = sWp[0] + sWp[1] + sWp[2] + sWp[3];
}

// ---------------- Pass D -----------------------------------------------------
__global__ __launch_bounds__(256) void pass_d(
    const float* __restrict__ part, float* __restrict__ out, float invN, int n)
{
  __shared__ float red[4];
  int t = threadIdx.x, w = t >> 6, lane = t & 63;
  float s = 0.f;
  for (int i = t; i < n; i += 256) s += part[i];
  s += __shfl_xor(s, 1);  s += __shfl_xor(s, 2);  s += __shfl_xor(s, 4);
  s += __shfl_xor(s, 8);  s += __shfl_xor(s, 16); s += __shfl_xor(s, 32);
  if (lane == 0) red[w] = s;
  __syncthreads();
  if (t == 0) out[0] = (red[0] + red[1] + red[2] + red[3]) * invN;
}

extern "C" void kernel_launch(void* const* d_in, const int* in_sizes, int n_in,
                              void* d_out, int out_size, void* d_ws, size_t ws_size,
                              hipStream_t stream) {
  const float* emb = (const float*)d_in[0];
  const int* fam = (const int*)d_in[1];
  int N = in_sizes[0] / D_DIM;               // 262144
  int blocksA = N / ROWS_A;                  // 512
  int blocksC = N / 128;                     // 2048

  // ws (float units): psum[512*8192] | protoB(8192 ushort) | part[2048]
  float* ws = (float*)d_ws;
  float* psum = ws;
  size_t off = (size_t)blocksA * (F_NUM * D_DIM);
  unsigned short* protoB = (unsigned short*)(ws + off); off += (F_NUM * D_DIM) / 2;
  float* part = ws + off;

  pass_a<<<blocksA, 256, 0, stream>>>(emb, fam, psum);
  pass_b<<<F_NUM, 256, 0, stream>>>(psum, protoB, blocksA);
  pass_c<<<blocksC, 256, 0, stream>>>(emb, fam, protoB, part);
  pass_d<<<1, 256, 0, stream>>>(part, (float*)d_out, 1.0f / (float)N, blocksC);
}